// Round 6
// baseline (211.233 us; speedup 1.0000x reference)
//
#include <hip/hip_runtime.h>

// CapsNet routing: N=32, C=32, D=16(=P*P), S=W*H=256, K=10, n_rout=3.
// FUSED single kernel: 1024 blocks x 256 threads, one (n,c) per block,
// ~31.5 KB LDS. __launch_bounds__(256,4) => VGPR<=128 => 4 blocks/CU by
// VGPR, 5 by LDS => capacity >= 1024 = grid => all blocks co-resident
// (no cooperative API -- not graph-capturable, round 1).
//
// Cross-block coupling (per-n sum of s over 32 c-blocks) uses ROUND-2's
// fully-validated protocol (it passed vs-ref + replay + post-timing over
// thousands of replays): device-scope atomicAdd accumulation into a shared
// per-n buffer, __syncthreads vmcnt(0) drain, RELEASE agent-scope counter
// inc (one per block -- cheap; per-wave fences are what storm), relaxed
// spin, relaxed single-address readback. The ONE change vs round 2:
// payload is FIXED-POINT INT64 (scale 2^32) via atomicAdd(u64). Integer
// adds commute exactly => bit-identical sum regardless of commit order =>
// replay-deterministic by construction (kills round 3's 9.8e-4 fp-ordering
// failure) on the RMW visibility path that already survived post-timing
// (kills rounds 4/5's stale-read leaks: atomicExch/plain-store paths are
// NOT reliably visible at vmcnt-retire; atomicAdd is).
// Quantization: err ~32*2^-33 ~ 4e-9 (threshold 1.8e-2); range
// |s|*2^32 <~ 1e4*4.3e9 ~ 4e13 << 2^63.

#define KK 10
#define PP 16
#define CC 32
#define SS 256
#define NN 32
#define RR 3
#define SE (KK * PP)   // 160 s-elements

typedef unsigned long long u64;
#define SCALE_F  4294967296.0f          // 2^32
#define INV_SCALE (1.0 / 4294967296.0)  // double

__global__ __launch_bounds__(256, 4) void fused_kernel(
    const float* __restrict__ l,       // [N][C][16][256]
    const float* __restrict__ w,       // [C][K][4][4]
    const float* __restrict__ g,       // [N][K][16]
    u64*   __restrict__ s_buf,         // [3][N][160] pre-zeroed, int64 accum
    int*   __restrict__ ctr,           // [3][N] pre-zeroed
    float* __restrict__ out_a,         // [N][K]
    float* __restrict__ out_gc)        // [N][K][16]
{
  const int bid = blockIdx.x;          // 0..1023
  const int n = bid >> 5;
  const int c = bid & 31;
  const int t = threadIdx.x;           // t == site index s in per-site phases

  __shared__ float lr_lds[PP][SS + 4];     // 16640 B
  __shared__ float ct_lds[KK][SS + 4];     // 10400 B
  __shared__ float U_lds[SE];              //   640 B (U; reused for M)
  __shared__ float w_lds[SE];              //   640 B
  __shared__ float gc_lds[SE];             //   640 B
  __shared__ float f_lds[KK];              //    40 B
  __shared__ float pmerge[4][SE];          //  2560 B per-wave M partials
  // total ~31.5 KB -> 5 blocks/CU by LDS, 4 by VGPR cap

  // ---- stage w[c], l slice (regs + LDS), g -- ONCE for all rounds ----
  if (t < SE) w_lds[t] = w[c * SE + t];
  float lr[PP];
  const float* lb = l + (size_t)(n * CC + c) * (PP * SS) + t;
  #pragma unroll
  for (int d = 0; d < PP; ++d) {
    lr[d] = lb[d * SS];                 // coalesced across t
    lr_lds[d][t] = lr[d];
  }
  if (t < SE) gc_lds[t] = g[n * SE + t];
  __syncthreads();

  #pragma unroll 1
  for (int r = 0; r < RR; ++r) {
    if (r > 0) {
      // gc_lds holds raw s_prev (deterministic int64 sum, dequantized)
      if (t < KK) {
        float sn = 0.f;
        #pragma unroll
        for (int m = 0; m < PP; ++m) { const float v = gc_lds[t * PP + m]; sn += v * v; }
        f_lds[t] = sn / (1.f + sn) * rsqrtf(sn);
      }
      __syncthreads();
      if (t < SE) gc_lds[t] *= f_lds[t >> 4];
      __syncthreads();
    }

    // ---- U[k][i*4+j] = sum_dd w[c,k,j,dd] * gc[k,i*4+dd] ----
    if (t < SE) {
      const int k = t >> 4, ij = t & 15, i = ij >> 2, j = ij & 3;
      const float4 wv = *(const float4*)&w_lds[k * PP + j * 4];
      const float4 gv = *(const float4*)&gc_lds[k * PP + i * 4];
      U_lds[t] = wv.x * gv.x + wv.y * gv.y + wv.z * gv.z + wv.w * gv.w;
    }
    __syncthreads();

    // ---- b[k] = lr . U[k]; softmax over k; store ct[k][s] ----
    {
      float b[KK];
      float bmax = -1e30f;
      #pragma unroll
      for (int k = 0; k < KK; ++k) {
        float acc = 0.f;
        #pragma unroll
        for (int d4 = 0; d4 < 4; ++d4) {
          const float4 uv = *(const float4*)&U_lds[k * PP + d4 * 4]; // wave-uniform: broadcast
          acc += lr[d4*4+0]*uv.x + lr[d4*4+1]*uv.y + lr[d4*4+2]*uv.z + lr[d4*4+3]*uv.w;
        }
        b[k] = acc;
        bmax = fmaxf(bmax, acc);
      }
      float ssum = 0.f;
      #pragma unroll
      for (int k = 0; k < KK; ++k) { b[k] = __expf(b[k] - bmax); ssum += b[k]; }
      const float inv = 1.f / ssum;
      #pragma unroll
      for (int k = 0; k < KK; ++k) ct_lds[k][t] = b[k] * inv;
    }
    __syncthreads();

    // ---- M[k][ij]: 16-site chunks in regs, wave-shuffle chunk merge ----
    {
      const int ch = t >> 4, ij = t & 15, sbase = ch * 16;
      float acc[KK];
      #pragma unroll
      for (int k = 0; k < KK; ++k) acc[k] = 0.f;
      #pragma unroll
      for (int s4 = 0; s4 < 4; ++s4) {
        const float4 lv = *(const float4*)&lr_lds[ij][sbase + s4 * 4];
        #pragma unroll
        for (int k = 0; k < KK; ++k) {
          const float4 cv = *(const float4*)&ct_lds[k][sbase + s4 * 4]; // 16-lane broadcast
          acc[k] += cv.x*lv.x + cv.y*lv.y + cv.z*lv.z + cv.w*lv.w;
        }
      }
      // wave covers chunks {4w..4w+3}: xor over lane bits 4,5 merges them
      #pragma unroll
      for (int k = 0; k < KK; ++k) {
        acc[k] += __shfl_xor(acc[k], 16);
        acc[k] += __shfl_xor(acc[k], 32);
      }
      const int wv = t >> 6;
      if ((t & 63) < 16) {
        #pragma unroll
        for (int k = 0; k < KK; ++k) pmerge[wv][k * PP + ij] = acc[k];
      }
    }
    __syncthreads();

    // ---- merge 4 waves' partials -> M (into U_lds; U is dead) ----
    if (t < SE) {
      U_lds[t] = pmerge[0][t] + pmerge[1][t] + pmerge[2][t] + pmerge[3][t];
    }
    __syncthreads();

    // ---- s-partial[k][i*4+d] = sum_j M[k][i*4+j]*w[c,k,j,d] ----
    // quantize (deterministic per block) + int64 atomicAdd (exact commute)
    u64* s_r = s_buf + (size_t)r * NN * SE;
    if (t < SE) {
      const int k = t >> 4, i = (t >> 2) & 3, d = t & 3;
      const float* Mp  = U_lds + k * PP + i * 4;
      const float* wpt = w_lds + k * PP + d;
      const float sv = Mp[0]*wpt[0] + Mp[1]*wpt[4] + Mp[2]*wpt[8] + Mp[3]*wpt[12];
      const long long q = llrintf(sv * SCALE_F);   // exact *2^32, round-ne
      atomicAdd(&s_r[n * SE + t], (u64)q);         // modular == int64 add
    }
    __syncthreads();   // per-wave vmcnt(0): block's adds are committed at
                       // the coherence point before t0 signals

    if (t == 0)
      __hip_atomic_fetch_add(&ctr[r * NN + n], 1,
                             __ATOMIC_RELEASE, __HIP_MEMORY_SCOPE_AGENT);

    if (r < RR - 1) {
      // per-n barrier over the 32 sibling c-blocks (guarded: no hard hang)
      if (t == 0) {
        int guard = 0;
        while (__hip_atomic_load(&ctr[r * NN + n],
                                 __ATOMIC_RELAXED, __HIP_MEMORY_SCOPE_AGENT) < CC
               && ++guard < (1 << 24))
          __builtin_amdgcn_s_sleep(2);
      }
      __syncthreads();
      // single-address coherent readback (round-2-proven), dequantize
      if (t < SE) {
        const u64 v = __hip_atomic_load(&s_r[n * SE + t],
                                        __ATOMIC_RELAXED, __HIP_MEMORY_SCOPE_AGENT);
        gc_lds[t] = (float)((double)(long long)v * INV_SCALE);
      }
      __syncthreads();
    }
  }

  // ---- final outputs: one block per n (c==0); others exit, freeing CUs ----
  if (c == 0) {
    u64* s2 = s_buf + (size_t)2 * NN * SE;
    if (t == 0) {
      int guard = 0;
      while (__hip_atomic_load(&ctr[2 * NN + n],
                               __ATOMIC_RELAXED, __HIP_MEMORY_SCOPE_AGENT) < CC
             && ++guard < (1 << 24))
        __builtin_amdgcn_s_sleep(2);
    }
    __syncthreads();
    if (t < SE) {
      const u64 v = __hip_atomic_load(&s2[n * SE + t],
                                      __ATOMIC_RELAXED, __HIP_MEMORY_SCOPE_AGENT);
      gc_lds[t] = (float)((double)(long long)v * INV_SCALE);
    }
    __syncthreads();
    if (t < KK) {
      float sn = 0.f;
      #pragma unroll
      for (int m = 0; m < PP; ++m) { const float v = gc_lds[t * PP + m]; sn += v * v; }
      f_lds[t] = sn / (1.f + sn) * rsqrtf(sn);
      const float gn = sn / (1.f + sn);          // = sqrt(sum gc^2)
      out_a[n * KK + t] = 1.f / (1.f + __expf(-gn));
    }
    __syncthreads();
    if (t < SE) out_gc[n * SE + t] = gc_lds[t] * f_lds[t >> 4];
  }
}

extern "C" void kernel_launch(void* const* d_in, const int* in_sizes, int n_in,
                              void* d_out, int out_size, void* d_ws, size_t ws_size,
                              hipStream_t stream) {
  const float* l = (const float*)d_in[0];
  const float* g = (const float*)d_in[1];
  const float* w = (const float*)d_in[2];

  float* out    = (float*)d_out;
  float* out_a  = out;
  float* out_gc = out + NN * KK;

  u64* s_buf = (u64*)d_ws;                               // [3][N][160] u64
  const size_t s_bytes = (size_t)RR * NN * SE * sizeof(u64);
  int* ctr   = (int*)((char*)d_ws + s_bytes);            // [3][N]
  // zero accumulators + counters (contiguous) each replay
  hipMemsetAsync(d_ws, 0, s_bytes + (size_t)RR * NN * sizeof(int), stream);

  fused_kernel<<<NN * CC, 256, 0, stream>>>(l, w, g, s_buf, ctr,
                                            out_a, out_gc);
}

// Round 9
// 141.296 us; speedup vs baseline: 1.4950x; 1.4950x over previous
//
#include <hip/hip_runtime.h>

// CapsNet routing: N=32, C=32, D=16(=P*P), S=W*H=256, K=10, n_rout=3.
// FUSED single kernel: 1024 blocks x 256 threads, one (n,c) per block,
// ~31.5 KB LDS. __launch_bounds__(256,4) => 4 blocks/CU by grid, 5 by LDS
// => all 1024 blocks co-resident (rocprof r6: Occupancy ~40%).
//
// Cross-block coupling (per-n sum of s over 32 c-blocks):
//   * payload: FIXED-POINT INT64 (scale 2^32), integer adds commute =>
//     bit-exact sum regardless of commit order (replay-deterministic).
//   * visibility (r9 fix): the data atomicAdd is a RETURNING RMW whose
//     result is consumed (asm sink). A returning atomic must deliver the
//     old value AT the location, so vmcnt-retire proves execution at the
//     coherence point. __syncthreads' vmcnt(0) drain then guarantees all
//     of this block's adds are globally visible BEFORE t0's relaxed flag.
//     History: no-return adds retire on pipeline-accept, not execute --
//     r8's relaxed+no-return leaked rarely (~1e-3 replay divergence);
//     r5's (void)atomicExch same story at 2.7e-2; r6's RELEASE flag was
//     correct but its buffer_wbl2 per-XCD L2-writeback storm cost
//     142us @ 7.3% VALUBusy (3072 releases/launch).
//   * flag inc + spin + readback: all RELAXED agent-scope (no
//     release/acquire anywhere => no wb/inv maintenance at all).

#define KK 10
#define PP 16
#define CC 32
#define SS 256
#define NN 32
#define RR 3
#define SE (KK * PP)   // 160 s-elements

typedef unsigned long long u64;
#define SCALE_F  4294967296.0f          // 2^32
#define INV_SCALE (1.0 / 4294967296.0)  // double

__global__ __launch_bounds__(256, 4) void fused_kernel(
    const float* __restrict__ l,       // [N][C][16][256]
    const float* __restrict__ w,       // [C][K][4][4]
    const float* __restrict__ g,       // [N][K][16]
    u64*   __restrict__ s_buf,         // [3][N][160] pre-zeroed, int64 accum
    int*   __restrict__ ctr,           // [3][N] pre-zeroed
    float* __restrict__ out_a,         // [N][K]
    float* __restrict__ out_gc)        // [N][K][16]
{
  const int bid = blockIdx.x;          // 0..1023
  const int n = bid >> 5;
  const int c = bid & 31;
  const int t = threadIdx.x;           // t == site index s in per-site phases

  __shared__ float lr_lds[PP][SS + 4];     // 16640 B
  __shared__ float ct_lds[KK][SS + 4];     // 10400 B
  __shared__ float U_lds[SE];              //   640 B (U; reused for M)
  __shared__ float w_lds[SE];              //   640 B
  __shared__ float gc_lds[SE];             //   640 B
  __shared__ float f_lds[KK];              //    40 B
  __shared__ float pmerge[4][SE];          //  2560 B per-wave M partials
  // total ~31.5 KB -> 5 blocks/CU by LDS; grid provides 4

  // ---- stage w[c], l slice (regs + LDS), g -- ONCE for all rounds ----
  if (t < SE) w_lds[t] = w[c * SE + t];
  float lr[PP];
  const float* lb = l + (size_t)(n * CC + c) * (PP * SS) + t;
  #pragma unroll
  for (int d = 0; d < PP; ++d) {
    lr[d] = lb[d * SS];                 // coalesced across t
    lr_lds[d][t] = lr[d];
  }
  if (t < SE) gc_lds[t] = g[n * SE + t];
  __syncthreads();

  #pragma unroll 1
  for (int r = 0; r < RR; ++r) {
    if (r > 0) {
      // gc_lds holds raw s_prev (deterministic int64 sum, dequantized)
      if (t < KK) {
        float sn = 0.f;
        #pragma unroll
        for (int m = 0; m < PP; ++m) { const float v = gc_lds[t * PP + m]; sn += v * v; }
        f_lds[t] = sn / (1.f + sn) * rsqrtf(sn);
      }
      __syncthreads();
      if (t < SE) gc_lds[t] *= f_lds[t >> 4];
      __syncthreads();
    }

    // ---- U[k][i*4+j] = sum_dd w[c,k,j,dd] * gc[k,i*4+dd] ----
    if (t < SE) {
      const int k = t >> 4, ij = t & 15, i = ij >> 2, j = ij & 3;
      const float4 wv = *(const float4*)&w_lds[k * PP + j * 4];
      const float4 gv = *(const float4*)&gc_lds[k * PP + i * 4];
      U_lds[t] = wv.x * gv.x + wv.y * gv.y + wv.z * gv.z + wv.w * gv.w;
    }
    __syncthreads();

    // ---- b[k] = lr . U[k]; softmax over k; store ct[k][s] ----
    {
      float b[KK];
      float bmax = -1e30f;
      #pragma unroll
      for (int k = 0; k < KK; ++k) {
        float acc = 0.f;
        #pragma unroll
        for (int d4 = 0; d4 < 4; ++d4) {
          const float4 uv = *(const float4*)&U_lds[k * PP + d4 * 4]; // wave-uniform: broadcast
          acc += lr[d4*4+0]*uv.x + lr[d4*4+1]*uv.y + lr[d4*4+2]*uv.z + lr[d4*4+3]*uv.w;
        }
        b[k] = acc;
        bmax = fmaxf(bmax, acc);
      }
      float ssum = 0.f;
      #pragma unroll
      for (int k = 0; k < KK; ++k) { b[k] = __expf(b[k] - bmax); ssum += b[k]; }
      const float inv = 1.f / ssum;
      #pragma unroll
      for (int k = 0; k < KK; ++k) ct_lds[k][t] = b[k] * inv;
    }
    __syncthreads();

    // ---- M[k][ij]: 16-site chunks in regs, wave-shuffle chunk merge ----
    {
      const int ch = t >> 4, ij = t & 15, sbase = ch * 16;
      float acc[KK];
      #pragma unroll
      for (int k = 0; k < KK; ++k) acc[k] = 0.f;
      #pragma unroll
      for (int s4 = 0; s4 < 4; ++s4) {
        const float4 lv = *(const float4*)&lr_lds[ij][sbase + s4 * 4];
        #pragma unroll
        for (int k = 0; k < KK; ++k) {
          const float4 cv = *(const float4*)&ct_lds[k][sbase + s4 * 4]; // 16-lane broadcast
          acc[k] += cv.x*lv.x + cv.y*lv.y + cv.z*lv.z + cv.w*lv.w;
        }
      }
      // wave covers chunks {4w..4w+3}: xor over lane bits 4,5 merges them
      #pragma unroll
      for (int k = 0; k < KK; ++k) {
        acc[k] += __shfl_xor(acc[k], 16);
        acc[k] += __shfl_xor(acc[k], 32);
      }
      const int wv = t >> 6;
      if ((t & 63) < 16) {
        #pragma unroll
        for (int k = 0; k < KK; ++k) pmerge[wv][k * PP + ij] = acc[k];
      }
    }
    __syncthreads();

    // ---- merge 4 waves' partials -> M (into U_lds; U is dead) ----
    if (t < SE) {
      U_lds[t] = pmerge[0][t] + pmerge[1][t] + pmerge[2][t] + pmerge[3][t];
    }
    __syncthreads();

    // ---- s-partial[k][i*4+d] = sum_j M[k][i*4+j]*w[c,k,j,d] ----
    // quantize (deterministic per block) + RETURNING u64 atomicAdd: the
    // consumed result forces the sc0 returning form, so vmcnt-retire ==
    // executed at the coherence point (the r9 visibility fix).
    u64* s_r = s_buf + (size_t)r * NN * SE;
    if (t < SE) {
      const int k = t >> 4, i = (t >> 2) & 3, d = t & 3;
      const float* Mp  = U_lds + k * PP + i * 4;
      const float* wpt = w_lds + k * PP + d;
      const float sv = Mp[0]*wpt[0] + Mp[1]*wpt[4] + Mp[2]*wpt[8] + Mp[3]*wpt[12];
      const long long q = llrintf(sv * SCALE_F);   // *2^32, round-ne
      u64 old = __hip_atomic_fetch_add(&s_r[n * SE + t], (u64)q,
                                       __ATOMIC_RELAXED,
                                       __HIP_MEMORY_SCOPE_AGENT);
      asm volatile("" :: "v"(old));   // consume: keep the returning form
    }
    __syncthreads();   // vmcnt(0) drain: returning RMWs have EXECUTED at
                       // the coherence point before t0 signals

    if (t == 0)
      __hip_atomic_fetch_add(&ctr[r * NN + n], 1,
                             __ATOMIC_RELAXED, __HIP_MEMORY_SCOPE_AGENT);

    if (r < RR - 1) {
      // per-n barrier over the 32 sibling c-blocks (guarded: no hard hang)
      if (t == 0) {
        int guard = 0;
        while (__hip_atomic_load(&ctr[r * NN + n],
                                 __ATOMIC_RELAXED, __HIP_MEMORY_SCOPE_AGENT) < CC
               && ++guard < (1 << 24))
          __builtin_amdgcn_s_sleep(2);
      }
      __syncthreads();
      // single-address coherent readback, dequantize
      if (t < SE) {
        const u64 v = __hip_atomic_load(&s_r[n * SE + t],
                                        __ATOMIC_RELAXED, __HIP_MEMORY_SCOPE_AGENT);
        gc_lds[t] = (float)((double)(long long)v * INV_SCALE);
      }
      __syncthreads();
    }
  }

  // ---- final outputs: one block per n (c==0); others exit, freeing CUs ----
  if (c == 0) {
    u64* s2 = s_buf + (size_t)2 * NN * SE;
    if (t == 0) {
      int guard = 0;
      while (__hip_atomic_load(&ctr[2 * NN + n],
                               __ATOMIC_RELAXED, __HIP_MEMORY_SCOPE_AGENT) < CC
             && ++guard < (1 << 24))
        __builtin_amdgcn_s_sleep(2);
    }
    __syncthreads();
    if (t < SE) {
      const u64 v = __hip_atomic_load(&s2[n * SE + t],
                                      __ATOMIC_RELAXED, __HIP_MEMORY_SCOPE_AGENT);
      gc_lds[t] = (float)((double)(long long)v * INV_SCALE);
    }
    __syncthreads();
    if (t < KK) {
      float sn = 0.f;
      #pragma unroll
      for (int m = 0; m < PP; ++m) { const float v = gc_lds[t * PP + m]; sn += v * v; }
      f_lds[t] = sn / (1.f + sn) * rsqrtf(sn);
      const float gn = sn / (1.f + sn);          // = sqrt(sum gc^2)
      out_a[n * KK + t] = 1.f / (1.f + __expf(-gn));
    }
    __syncthreads();
    if (t < SE) out_gc[n * SE + t] = gc_lds[t] * f_lds[t >> 4];
  }
}

extern "C" void kernel_launch(void* const* d_in, const int* in_sizes, int n_in,
                              void* d_out, int out_size, void* d_ws, size_t ws_size,
                              hipStream_t stream) {
  const float* l = (const float*)d_in[0];
  const float* g = (const float*)d_in[1];
  const float* w = (const float*)d_in[2];

  float* out    = (float*)d_out;
  float* out_a  = out;
  float* out_gc = out + NN * KK;

  u64* s_buf = (u64*)d_ws;                               // [3][N][160] u64
  const size_t s_bytes = (size_t)RR * NN * SE * sizeof(u64);
  int* ctr   = (int*)((char*)d_ws + s_bytes);            // [3][N]
  // zero accumulators + counters (contiguous) each replay
  hipMemsetAsync(d_ws, 0, s_bytes + (size_t)RR * NN * sizeof(int), stream);

  fused_kernel<<<NN * CC, 256, 0, stream>>>(l, w, g, s_buf, ctr,
                                            out_a, out_gc);
}